// Round 13
// baseline (192.999 us; speedup 1.0000x reference)
//
#include <hip/hip_runtime.h>

// LoRA: out = x @ (A@B) * 1.0, computed as (x@A)@B, FUSED in one kernel.
// x: [M=16384, K=4096] f32, A: [K, 16] f32, B: [16, N=4096] f32.
// r9 skeleton (best: 129.7us) + two ILP changes ONLY:
//   (1) __launch_bounds__(256,4): occupancy is LDS-bound at 4 blocks/CU
//       (33KB/block), so declare 4 waves/EU and raise the VGPR cap to 128 --
//       r1/r12 showed the compiler self-caps at 52-64 VGPR chasing occupancy
//       that LDS already forbids, strangling load ILP.
//   (2) Explicit 2-stage x prefetch: kb+1's loads issued into named xn[]
//       before kb's FMA block (wave always has ~1KB outstanding); chunk's
//       kb0 loads issued BEFORE the staging loads to overlap stage latency.
constexpr int RANK = 16;
constexpr int K = 4096;
constexpr int N = 4096;
constexpr int M = 4 * 4096;
constexpr int KC = 512;       // K-chunk staged in LDS (512 rows x 64B = 32KB)
constexpr int NCHUNK = K / KC;

__global__ __launch_bounds__(256, 4) void lora_fused(const float* __restrict__ x,
                                                     const float* __restrict__ A,
                                                     const float* __restrict__ B,
                                                     float* __restrict__ out) {
  const int lane = threadIdx.x & 63;
  const int tid = threadIdx.x;
  const int wave = tid >> 6;
  const int rbase = blockIdx.x * 16;
  const int r0 = rbase + wave * 4;  // this wave's 4 rows (phase 1)
  const int m = (lane >> 2) & 3;

  __shared__ float4 As[KC * 4];     // 32 KB, swizzled A chunk (r2 layout)
  __shared__ float Ts[16][RANK];    // 1 KB, block's T-tile

  const float4* __restrict__ A4 = reinterpret_cast<const float4*>(A);

  // ================= Phase 1: T-tile = x @ A =============
  float vals[64];
#pragma unroll
  for (int i = 0; i < 64; ++i) vals[i] = 0.0f;

  for (int c = 0; c < NCHUNK; ++c) {
    __syncthreads();  // previous chunk's readers done

    // Issue kb0's x loads FIRST (independent of LDS): they fly during staging.
    float xc[4], xn[4];
#pragma unroll
    for (int r = 0; r < 4; ++r)
      xc[r] = x[(size_t)(r0 + r) * K + (size_t)c * KC + lane];

    // ---- stage chunk c: KC*4 = 2048 float4 slots, 8 per thread (r2) ----
    // slot s of row k stored at p = s ^ ((k>>2)&3)
#pragma unroll
    for (int q = 0; q < 8; ++q) {
      const int n = q * 256 + tid;              // slot index 0..2047
      const int k = n >> 2;                     // local row
      const int s = n & 3;                      // true slot
      const int p = s ^ ((k >> 2) & 3);         // swizzled position
      As[k * 4 + p] = A4[(size_t)c * 2048 + n];
    }
    __syncthreads();

    // ---- compute: 8 k-blocks of 64 (one k per lane), 2-stage x pipeline ----
#pragma unroll
    for (int kbi = 0; kbi < 8; ++kbi) {
      // prefetch kb+1's x while this kb computes
      if (kbi + 1 < 8) {
        const size_t kgn = (size_t)c * KC + (kbi + 1) * 64 + lane;
#pragma unroll
        for (int r = 0; r < 4; ++r) xn[r] = x[(size_t)(r0 + r) * K + kgn];
      }

      const int kl = kbi * 64 + lane;           // local k in chunk
      float4 a[4];
#pragma unroll
      for (int s = 0; s < 4; ++s) a[s] = As[kl * 4 + (s ^ m)];

#pragma unroll
      for (int r = 0; r < 4; ++r) {
#pragma unroll
        for (int s = 0; s < 4; ++s) {
          vals[r * 16 + 4 * s + 0] = fmaf(xc[r], a[s].x, vals[r * 16 + 4 * s + 0]);
          vals[r * 16 + 4 * s + 1] = fmaf(xc[r], a[s].y, vals[r * 16 + 4 * s + 1]);
          vals[r * 16 + 4 * s + 2] = fmaf(xc[r], a[s].z, vals[r * 16 + 4 * s + 2]);
          vals[r * 16 + 4 * s + 3] = fmaf(xc[r], a[s].w, vals[r * 16 + 4 * s + 3]);
        }
      }

#pragma unroll
      for (int r = 0; r < 4; ++r) xc[r] = xn[r];  // rotate pipeline regs
    }
  }

  // Reduce-scatter (r2, proven): lane i ends with element i (r=i>>4, j=i&15).
#define RSTEP(HALF)                                            \
  {                                                            \
    const bool hi = (lane & (HALF)) != 0;                      \
    _Pragma("unroll")                                          \
    for (int i = 0; i < (HALF); ++i) {                         \
      const float send = hi ? vals[i] : vals[i + (HALF)];      \
      const float keep = hi ? vals[i + (HALF)] : vals[i];      \
      vals[i] = keep + __shfl_xor(send, (HALF), 64);           \
    }                                                          \
  }
  RSTEP(32)
  RSTEP(16)
  RSTEP(8)
  RSTEP(4)
  RSTEP(2)
  RSTEP(1)
#undef RSTEP

  // Hand off T-tile via LDS (1 write/lane, conflict-free).
  Ts[wave * 4 + (lane >> 4)][lane & 15] = vals[0];
  __syncthreads();

  // ================= Phase 2: out-tile = T-tile @ B (r9, proven) ==========
  const float4* __restrict__ B4 = reinterpret_cast<const float4*>(B);
  float4* __restrict__ out4 = reinterpret_cast<float4*>(out);

#pragma unroll 1
  for (int cc = 0; cc < 4; ++cc) {
    const int col = wave * 1024 + cc * 256 + lane * 4;

    float4 b[16];
#pragma unroll
    for (int j = 0; j < RANK; ++j) b[j] = B4[((size_t)j * N + col) >> 2];

#pragma unroll 1
    for (int r = 0; r < 16; ++r) {
      // Broadcast T row r (same addr all lanes -> free LDS broadcast).
      const float4* __restrict__ tr4 =
          reinterpret_cast<const float4*>(&Ts[r][0]);
      const float4 t0 = tr4[0];
      const float4 t1 = tr4[1];
      const float4 t2 = tr4[2];
      const float4 t3 = tr4[3];

      float4 acc;
      acc.x = acc.y = acc.z = acc.w = 0.0f;
      const float tsv[16] = {t0.x, t0.y, t0.z, t0.w, t1.x, t1.y, t1.z, t1.w,
                             t2.x, t2.y, t2.z, t2.w, t3.x, t3.y, t3.z, t3.w};
#pragma unroll
      for (int j = 0; j < RANK; ++j) {
        acc.x = fmaf(tsv[j], b[j].x, acc.x);
        acc.y = fmaf(tsv[j], b[j].y, acc.y);
        acc.z = fmaf(tsv[j], b[j].z, acc.z);
        acc.w = fmaf(tsv[j], b[j].w, acc.w);
      }
      out4[((size_t)(rbase + r) * N + col) >> 2] = acc;
    }
  }
}

extern "C" void kernel_launch(void* const* d_in, const int* in_sizes, int n_in,
                              void* d_out, int out_size, void* d_ws, size_t ws_size,
                              hipStream_t stream) {
  const float* x = (const float*)d_in[0];   // [M, K]
  const float* A = (const float*)d_in[1];   // [K, RANK]
  const float* B = (const float*)d_in[2];   // [RANK, N]
  float* out = (float*)d_out;               // [M, N]
  (void)d_ws; (void)ws_size;

  // One fused kernel: 16 rows per block -> 1024 blocks.
  lora_fused<<<M / 16, 256, 0, stream>>>(x, A, B, out);
}

// Round 14
// 138.577 us; speedup vs baseline: 1.3927x; 1.3927x over previous
//
#include <hip/hip_runtime.h>

// LoRA: out = x @ (A@B) * 1.0, computed as (x@A)@B, FUSED, TLP-first.
// x: [M=16384, K=4096] f32, A: [K, 16] f32, B: [16, N=4096] f32.
//
// == r11 with the launch_bounds strangler removed (the ONLY change). ==
// r11/r12/r13 established: hipcc targets ~64 VGPR for these kernels; hints
// (512,6)/(256,4) only strangle regalloc (VGPR 40) or induce spills. So:
// pick a body whose live state FITS 64 regs and ride the compiler's habit
// to 8 waves/SIMD = 32 waves/CU (2x r9's TLP -> 2x outstanding read bytes).
//
// Phase 1: 512-thr blocks, 16 rows. Wave w = (row-group rg=w&3, j-half
// jg=w>>2): 4 rows x 8 j -> vals[32]; 2 ds_read_b128 per 32 FMAs (same
// amortization as r9's proven body). x loads scalar dword (r2-proven);
// j-half pairs load identical x addresses (L1 broadcast).
// Phase 2: r11's float2 T@B (32-reg B fragment, write-roofline-bound).

constexpr int RANK = 16;
constexpr int K = 4096;
constexpr int N = 4096;
constexpr int M = 4 * 4096;
constexpr int KC = 512;        // K-chunk staged in LDS (512 rows x 64B = 32KB)
constexpr int NCHUNK = K / KC; // 8

__global__ __launch_bounds__(512) void lora_fused(const float* __restrict__ x,
                                                  const float* __restrict__ A,
                                                  const float* __restrict__ B,
                                                  float* __restrict__ out) {
  const int tid = threadIdx.x;
  const int lane = tid & 63;
  const int w = tid >> 6;
  const int rg = w & 3;        // row group (4 rows)
  const int jg = w >> 2;       // j half (8 of 16 outputs)
  const int rbase = blockIdx.x * 16;
  const int r0 = rbase + rg * 4;
  const int m = (lane >> 2) & 3;

  __shared__ float4 As[KC * 4];  // 32 KB, swizzled A chunk (r2 layout)
  __shared__ float Ts[16][RANK]; // 1 KB, block's T-tile

  const float4* __restrict__ A4 = reinterpret_cast<const float4*>(A);

  // ================= Phase 1: T-tile = x @ A =============
  float vals[32];
#pragma unroll
  for (int i = 0; i < 32; ++i) vals[i] = 0.0f;

  for (int c = 0; c < NCHUNK; ++c) {
    __syncthreads();  // previous chunk's readers done
    // ---- stage chunk c: 2048 float4 slots, 4 per thread (512 thr) ----
    // slot s of row k stored at p = s ^ ((k>>2)&3)  (r2 swizzle, proven)
#pragma unroll
    for (int q = 0; q < 4; ++q) {
      const int n = q * 512 + tid;              // slot index 0..2047
      const int k = n >> 2;                     // local row
      const int s = n & 3;                      // true slot
      const int p = s ^ ((k >> 2) & 3);         // swizzled position
      As[k * 4 + p] = A4[(size_t)c * 2048 + n];
    }
    __syncthreads();

    // ---- compute: 8 k-blocks of 64 (one k per lane) ----
#pragma unroll
    for (int kbi = 0; kbi < 8; ++kbi) {
      const int kl = kbi * 64 + lane;           // local k in chunk
      const size_t kg = (size_t)c * KC + kl;    // global k

      float xv[4];
#pragma unroll
      for (int r = 0; r < 4; ++r) xv[r] = x[(size_t)(r0 + r) * K + kg];

      // this wave's 2 j-slots (j = jg*8 .. jg*8+7), swizzle-inverted read:
      // 4 distinct 16B slots x 2 lanes per 128B bank period = free.
      float4 a[2];
#pragma unroll
      for (int ss = 0; ss < 2; ++ss)
        a[ss] = As[kl * 4 + ((2 * jg + ss) ^ m)];

#pragma unroll
      for (int r = 0; r < 4; ++r) {
#pragma unroll
        for (int ss = 0; ss < 2; ++ss) {
          vals[r * 8 + ss * 4 + 0] = fmaf(xv[r], a[ss].x, vals[r * 8 + ss * 4 + 0]);
          vals[r * 8 + ss * 4 + 1] = fmaf(xv[r], a[ss].y, vals[r * 8 + ss * 4 + 1]);
          vals[r * 8 + ss * 4 + 2] = fmaf(xv[r], a[ss].z, vals[r * 8 + ss * 4 + 2]);
          vals[r * 8 + ss * 4 + 3] = fmaf(xv[r], a[ss].w, vals[r * 8 + ss * 4 + 3]);
        }
      }
    }
  }

  // 5-fold reduce-scatter over lane bits {32,16,8,4,2} (r11-proven), then
  // butterfly over bit 1: even lane 2e holds element e (row e>>3, jj e&7).
#define FOLD(AH, LB)                                           \
  {                                                            \
    const bool hi = (lane & (LB)) != 0;                        \
    _Pragma("unroll")                                          \
    for (int i = 0; i < (AH); ++i) {                           \
      const float send = hi ? vals[i] : vals[i + (AH)];        \
      const float keep = hi ? vals[i + (AH)] : vals[i];        \
      vals[i] = keep + __shfl_xor(send, (LB), 64);             \
    }                                                          \
  }
  FOLD(16, 32)
  FOLD(8, 16)
  FOLD(4, 8)
  FOLD(2, 4)
  FOLD(1, 2)
#undef FOLD
  vals[0] += __shfl_xor(vals[0], 1, 64);

  if (!(lane & 1)) {
    const int e = lane >> 1;  // 0..31
    Ts[rg * 4 + (e >> 3)][jg * 8 + (e & 7)] = vals[0];
  }
  __syncthreads();

  // ================= Phase 2: out-tile = T-tile @ B (r11-proven) ==========
  // Wave w owns cols [w*512, w*512+512), 4 passes of 128 cols (float2/lane).
  const float2* __restrict__ B2 = reinterpret_cast<const float2*>(B);
  float2* __restrict__ out2 = reinterpret_cast<float2*>(out);

#pragma unroll 1
  for (int cc = 0; cc < 4; ++cc) {
    const int col = w * 512 + cc * 128 + lane * 2;

    float2 b[16];  // 32 VGPRs (keeps phase-2 peak under phase-1's)
#pragma unroll
    for (int j = 0; j < RANK; ++j) b[j] = B2[((size_t)j * N + col) >> 1];

#pragma unroll 1
    for (int r = 0; r < 16; ++r) {
      // Broadcast T row r (same addr all lanes -> free LDS broadcast).
      const float4* __restrict__ tr4 =
          reinterpret_cast<const float4*>(&Ts[r][0]);
      const float4 t0 = tr4[0];
      const float4 t1 = tr4[1];
      const float4 t2 = tr4[2];
      const float4 t3 = tr4[3];
      const float tsv[16] = {t0.x, t0.y, t0.z, t0.w, t1.x, t1.y, t1.z, t1.w,
                             t2.x, t2.y, t2.z, t2.w, t3.x, t3.y, t3.z, t3.w};

      float2 acc;
      acc.x = acc.y = 0.0f;
#pragma unroll
      for (int j = 0; j < RANK; ++j) {
        acc.x = fmaf(tsv[j], b[j].x, acc.x);
        acc.y = fmaf(tsv[j], b[j].y, acc.y);
      }
      out2[((size_t)(rbase + r) * N + col) >> 1] = acc;
    }
  }
}

extern "C" void kernel_launch(void* const* d_in, const int* in_sizes, int n_in,
                              void* d_out, int out_size, void* d_ws, size_t ws_size,
                              hipStream_t stream) {
  const float* x = (const float*)d_in[0];   // [M, K]
  const float* A = (const float*)d_in[1];   // [K, RANK]
  const float* B = (const float*)d_in[2];   // [RANK, N]
  float* out = (float*)d_out;               // [M, N]
  (void)d_ws; (void)ws_size;

  // One fused kernel: 16 rows per block -> 1024 blocks of 512 threads.
  lora_fused<<<M / 16, 512, 0, stream>>>(x, A, B, out);
}